// Round 4
// baseline (261.514 us; speedup 1.0000x reference)
//
#include <hip/hip_runtime.h>
#include <hip/hip_bf16.h>
#include <math.h>

// Problem constants (fixed by the reference)
#define NSEG 32
#define T_DIM 8
#define F_DIM 32
#define P_DIM 8
#define OUT_PER_SEG 2048 // T*P*F
#define EPS_DENOM 1e-16f
#define CHUNK 128        // nodes per accum block

// Tiny MLP: h = elu(pos @ W1 + b1) @ W2 + b2  (per node, P=8 outputs)
__device__ __forceinline__ void compute_h(
    float h[P_DIM], const float* __restrict__ pos, int n,
    const float* __restrict__ W1, const float* __restrict__ b1,
    const float* __restrict__ W2, const float* __restrict__ b2) {
  float p0 = pos[3 * n + 0];
  float p1 = pos[3 * n + 1];
  float p2 = pos[3 * n + 2];
  float a[P_DIM];
#pragma unroll
  for (int p = 0; p < P_DIM; p++) {
    float v = b1[p] + p0 * W1[0 * P_DIM + p] + p1 * W1[1 * P_DIM + p] + p2 * W1[2 * P_DIM + p];
    a[p] = v > 0.f ? v : (__expf(v) - 1.f);  // ELU alpha=1
  }
#pragma unroll
  for (int p = 0; p < P_DIM; p++) {
    float v = b2[p];
#pragma unroll
    for (int j = 0; j < P_DIM; j++) v += a[j] * W2[j * P_DIM + p];
    h[p] = v;
  }
}

// Kernel 1: one pass over nodes. Computes e[n][p] = exp(h[n][p]) (no max
// shift: |h| is small for this MLP, fp32 exp is safe; R3 verified absmax
// 4.9e-4 vs 1.16e-2 threshold), stores e8[N][8] for the accum kernel's
// phase A, and accumulates per-segment sums via wave-reduced atomics.
__global__ __launch_bounds__(256) void weights_kernel(
    const float* __restrict__ pos, const int* __restrict__ seg,
    const float* __restrict__ W1, const float* __restrict__ b1,
    const float* __restrict__ W2, const float* __restrict__ b2,
    float* __restrict__ e8, float* __restrict__ sSum, int N) {
  int tid = threadIdx.x;
  int n = blockIdx.x * 256 + tid;
  bool valid = n < N;
  int nn = valid ? n : N - 1;
  int sg = seg[nn];
  float h[P_DIM];
  compute_h(h, pos, nn, W1, b1, W2, b2);
  float e[P_DIM];
#pragma unroll
  for (int p = 0; p < P_DIM; p++) e[p] = valid ? __expf(h[p]) : 0.f;
  if (valid) {
    float4* dst = (float4*)e8 + (size_t)n * 2;
    dst[0] = make_float4(e[0], e[1], e[2], e[3]);
    dst[1] = make_float4(e[4], e[5], e[6], e[7]);
  }
  int sg0 = __shfl(sg, 0, 64);
  if (__all(sg == sg0)) {
#pragma unroll
    for (int off = 32; off >= 1; off >>= 1)
#pragma unroll
      for (int p = 0; p < P_DIM; p++) e[p] += __shfl_down(e[p], off, 64);
    if ((tid & 63) == 0) {
#pragma unroll
      for (int p = 0; p < P_DIM; p++) unsafeAtomicAdd(&sSum[sg * 8 + p], e[p]);
    }
  } else if (valid) {
#pragma unroll
    for (int p = 0; p < P_DIM; p++) unsafeAtomicAdd(&sSum[sg * 8 + p], e[p]);
  }
}

// 32 atomic f32 adds for one wave-lane (slow path only)
__device__ __forceinline__ void flush32(float* __restrict__ out, int sg, int t,
                                        int f4, float4 acc4[P_DIM]) {
  float* bo = out + sg * OUT_PER_SEG + t * (P_DIM * F_DIM) + f4 * 4;
#pragma unroll
  for (int p = 0; p < P_DIM; p++) {
    unsafeAtomicAdd(bo + p * F_DIM + 0, acc4[p].x);
    unsafeAtomicAdd(bo + p * F_DIM + 1, acc4[p].y);
    unsafeAtomicAdd(bo + p * F_DIM + 2, acc4[p].z);
    unsafeAtomicAdd(bo + p * F_DIM + 3, acc4[p].w);
    acc4[p] = make_float4(0.f, 0.f, 0.f, 0.f);
  }
}

#define FMA_NODE(XV, WA, WB)                                                   \
  do {                                                                         \
    acc4[0].x += (XV).x * (WA).x; acc4[0].y += (XV).y * (WA).x;                \
    acc4[0].z += (XV).z * (WA).x; acc4[0].w += (XV).w * (WA).x;                \
    acc4[1].x += (XV).x * (WA).y; acc4[1].y += (XV).y * (WA).y;                \
    acc4[1].z += (XV).z * (WA).y; acc4[1].w += (XV).w * (WA).y;                \
    acc4[2].x += (XV).x * (WA).z; acc4[2].y += (XV).y * (WA).z;                \
    acc4[2].z += (XV).z * (WA).z; acc4[2].w += (XV).w * (WA).z;                \
    acc4[3].x += (XV).x * (WA).w; acc4[3].y += (XV).y * (WA).w;                \
    acc4[3].z += (XV).z * (WA).w; acc4[3].w += (XV).w * (WA).w;                \
    acc4[4].x += (XV).x * (WB).x; acc4[4].y += (XV).y * (WB).x;                \
    acc4[4].z += (XV).z * (WB).x; acc4[4].w += (XV).w * (WB).x;                \
    acc4[5].x += (XV).x * (WB).y; acc4[5].y += (XV).y * (WB).y;                \
    acc4[5].z += (XV).z * (WB).y; acc4[5].w += (XV).w * (WB).y;                \
    acc4[6].x += (XV).x * (WB).z; acc4[6].y += (XV).y * (WB).z;                \
    acc4[6].z += (XV).z * (WB).z; acc4[6].w += (XV).w * (WB).z;                \
    acc4[7].x += (XV).x * (WB).w; acc4[7].y += (XV).y * (WB).w;                \
    acc4[7].z += (XV).z * (WB).w; acc4[7].w += (XV).w * (WB).w;                \
  } while (0)

// consume 8 preloaded node rows (nodes w + 4*(OFF+j))
#define CONSUME(BUF, OFF)                                                      \
  do {                                                                         \
    _Pragma("unroll")                                                          \
    for (int j = 0; j < 8; j++) {                                              \
      int nd = w + 4 * ((OFF) + j);                                            \
      float4 wa = *(const float4*)&wbuf[nd][0];                                \
      float4 wb = *(const float4*)&wbuf[nd][4];                                \
      FMA_NODE(BUF[j], wa, wb);                                                \
    }                                                                          \
  } while (0)

// Kernel 2: heavy accumulation. Block = 256 thr (4 waves) owns CHUNK=128
// consecutive nodes. Phase A: thr<128 load e8 row (2 coalesced float4) and
// normalize -> wbuf. Phase B: explicit modulo-2 software pipeline: two named
// 8x float4 buffers; load group g+1 while consuming group g, so 8 KB/wave
// stays in flight continuously (R3's VGPR=52 showed the compiler had
// serialized the loads -> latency-bound at 14% HBM). launch_bounds(256,4)
// caps VGPR at 128 (need ~110). Flush: output-order flat redbuf, contiguous
// ds_read_b128 + 8 contiguous atomics/thread (1.6M total, same as R3).
__global__ __launch_bounds__(256, 4) void accum_kernel(
    const float* __restrict__ x, const int* __restrict__ seg,
    const float* __restrict__ e8, const float* __restrict__ sSum,
    float* __restrict__ out, int N) {
  __shared__ __align__(16) float wbuf[CHUNK][P_DIM];   // 4 KB
  __shared__ int sbuf[CHUNK];                          // 512 B
  __shared__ __align__(16) float redbuf[4][OUT_PER_SEG]; // 32 KB, output order

  int tid = threadIdx.x;
  int base = blockIdx.x * CHUNK;
  int cnt = N - base;
  if (cnt > CHUNK) cnt = CHUNK;

  if (tid < cnt) {
    int n = base + tid;
    int sg = seg[n];
    sbuf[tid] = sg;
    float4 e0 = ((const float4*)e8)[(size_t)n * 2 + 0];
    float4 e1 = ((const float4*)e8)[(size_t)n * 2 + 1];
    const float* sp = sSum + sg * 8;
    wbuf[tid][0] = e0.x / (sp[0] + EPS_DENOM);
    wbuf[tid][1] = e0.y / (sp[1] + EPS_DENOM);
    wbuf[tid][2] = e0.z / (sp[2] + EPS_DENOM);
    wbuf[tid][3] = e0.w / (sp[3] + EPS_DENOM);
    wbuf[tid][4] = e1.x / (sp[4] + EPS_DENOM);
    wbuf[tid][5] = e1.y / (sp[5] + EPS_DENOM);
    wbuf[tid][6] = e1.z / (sp[6] + EPS_DENOM);
    wbuf[tid][7] = e1.w / (sp[7] + EPS_DENOM);
  }
  __syncthreads();

  int w = tid >> 6, lane = tid & 63;
  int t = lane >> 3, f4 = lane & 7;
  const float4* xq = (const float4*)x + (size_t)base * 64 + lane;

  float4 acc4[P_DIM];
#pragma unroll
  for (int p = 0; p < P_DIM; p++) acc4[p] = make_float4(0.f, 0.f, 0.f, 0.f);

  bool fast = (cnt == CHUNK) && (sbuf[0] == sbuf[CHUNK - 1]);

  if (fast) {
    // wave w covers nodes w + 4k, k = 0..31 : 4 groups of 8, 2-buffer pipeline
    float4 xa[8], xb[8];
#pragma unroll
    for (int j = 0; j < 8; j++) xa[j] = xq[(size_t)(w + 4 * j) * 64];
#pragma unroll
    for (int j = 0; j < 8; j++) xb[j] = xq[(size_t)(w + 4 * (8 + j)) * 64];
    CONSUME(xa, 0);
#pragma unroll
    for (int j = 0; j < 8; j++) xa[j] = xq[(size_t)(w + 4 * (16 + j)) * 64];
    CONSUME(xb, 8);
#pragma unroll
    for (int j = 0; j < 8; j++) xb[j] = xq[(size_t)(w + 4 * (24 + j)) * 64];
    CONSUME(xa, 16);
    CONSUME(xb, 24);

    // stage this wave's partials in output-flat order
    float* rb = &redbuf[w][t * (P_DIM * F_DIM) + f4 * 4];
#pragma unroll
    for (int p = 0; p < P_DIM; p++) *(float4*)(rb + p * F_DIM) = acc4[p];
    __syncthreads();

    // block flush: thread owns 8 contiguous output words
    int sg = sbuf[0];
    float* bo = out + sg * OUT_PER_SEG + 8 * tid;
#pragma unroll
    for (int half = 0; half < 2; half++) {
      float4 v0 = *(const float4*)&redbuf[0][8 * tid + 4 * half];
      float4 v1 = *(const float4*)&redbuf[1][8 * tid + 4 * half];
      float4 v2 = *(const float4*)&redbuf[2][8 * tid + 4 * half];
      float4 v3 = *(const float4*)&redbuf[3][8 * tid + 4 * half];
      unsafeAtomicAdd(bo + 4 * half + 0, v0.x + v1.x + v2.x + v3.x);
      unsafeAtomicAdd(bo + 4 * half + 1, v0.y + v1.y + v2.y + v3.y);
      unsafeAtomicAdd(bo + 4 * half + 2, v0.z + v1.z + v2.z + v3.z);
      unsafeAtomicAdd(bo + 4 * half + 3, v0.w + v1.w + v2.w + v3.w);
    }
  } else {
    // generic: partial chunk and/or segment boundary inside chunk (rare)
    if (w < cnt) {
      int cur = sbuf[w];
      for (int nd = w; nd < cnt; nd += 4) {
        int sgi = sbuf[nd];
        if (sgi != cur) {
          flush32(out, cur, t, f4, acc4);
          cur = sgi;
        }
        float4 xv = xq[(size_t)nd * 64];
        float4 wa = *(const float4*)&wbuf[nd][0];
        float4 wb = *(const float4*)&wbuf[nd][4];
        FMA_NODE(xv, wa, wb);
      }
      flush32(out, cur, t, f4, acc4);
    }
  }
}

extern "C" void kernel_launch(void* const* d_in, const int* in_sizes, int n_in,
                              void* d_out, int out_size, void* d_ws, size_t ws_size,
                              hipStream_t stream) {
  const float* pos = (const float*)d_in[0];
  const float* x   = (const float*)d_in[1];
  const int*   seg = (const int*)d_in[2];
  const float* W1  = (const float*)d_in[3];
  const float* b1  = (const float*)d_in[4];
  const float* W2  = (const float*)d_in[5];
  const float* b2  = (const float*)d_in[6];
  float* out = (float*)d_out;
  int N = in_sizes[2];

  float* sSum = (float*)d_ws;         // [32][8] sum of exp (1 KB)
  float* e8   = (float*)d_ws + 256;   // [N][8] exp(h) rows (3.2 MB)

  hipMemsetAsync(d_out, 0, (size_t)out_size * sizeof(float), stream);
  hipMemsetAsync(d_ws, 0, NSEG * 8 * sizeof(float), stream);

  int nb = (N + 255) / 256;
  weights_kernel<<<nb, 256, 0, stream>>>(pos, seg, W1, b1, W2, b2, e8, sSum, N);

  int nblk = (N + CHUNK - 1) / CHUNK;
  accum_kernel<<<nblk, 256, 0, stream>>>(x, seg, e8, sSum, out, N);
}